// Round 3
// baseline (607.434 us; speedup 1.0000x reference)
//
#include <hip/hip_runtime.h>

#define N_SRC 100000
#define N_DST 20000
#define NE    1250000
#define D     64
#define NEG_SLOPE 0.2f

#define NBKT 1250      // buckets of 16 dsts: bucket = dst >> 4
#define BCAP 1536      // capacity per bucket (mean 1000, std ~32)
#define TILE 4096      // edges per pass-A block

// ---- float <-> ordered-uint encoding for atomicMax on floats ----
__device__ __forceinline__ unsigned enc_f32(float f) {
    unsigned u = __float_as_uint(f);
    return (u & 0x80000000u) ? ~u : (u | 0x80000000u);
}
__device__ __forceinline__ float dec_f32(unsigned u) {
    unsigned b = (u & 0x80000000u) ? (u ^ 0x80000000u) : ~u;
    return __uint_as_float(b);
}
#define ENC_NEG_INF 0x007FFFFFu

__device__ __forceinline__ unsigned short f2bf(float f) {
    unsigned u = __float_as_uint(f);
    u += 0x7FFFu + ((u >> 16) & 1);   // RNE
    return (unsigned short)(u >> 16);
}
__device__ __forceinline__ float bf2f(unsigned short b) {
    return __uint_as_float(((unsigned)b) << 16);
}

// ---- K0: wad[k] = W[k,:]@att_dst  +  init bucket cursors ----
__global__ void k_wad_init(const float* __restrict__ W,
                           const float* __restrict__ att_dst,
                           float* __restrict__ wad, int* __restrict__ gcur) {
    int g = blockIdx.x * 256 + threadIdx.x;
    if (g < NBKT) gcur[g] = g * BCAP;
    if (g < D) {
        float s = 0.f;
#pragma unroll
        for (int c = 0; c < D; ++c) s += W[g * D + c] * att_dst[c];
        wad[g] = s;
    }
}

// ---- K1: h = x @ W (bf16 out), a_src = h @ att_src.  64x64 tile, 4x4 reg ----
__global__ __launch_bounds__(256) void k_h(const float* __restrict__ x,
                                           const float* __restrict__ W,
                                           const float* __restrict__ att_src,
                                           unsigned short* __restrict__ hb,
                                           float* __restrict__ a_src) {
    __shared__ float xs[64 * 65];   // padded: bank-conflict-free row reads
    __shared__ float Ws[64 * 64];
    int t = threadIdx.x;
    int row0 = blockIdx.x * 64;
    int nrows = N_SRC - row0; if (nrows > 64) nrows = 64;
    {
        const float4* W4 = (const float4*)W;
        float4* Ws4 = (float4*)Ws;
#pragma unroll
        for (int p = 0; p < 4; ++p) Ws4[t + 256 * p] = W4[t + 256 * p];
    }
#pragma unroll
    for (int p = 0; p < 4; ++p) {
        int idx = t + 256 * p;            // 0..1023
        int r = idx >> 4, kq = idx & 15;
        float4 v = make_float4(0.f, 0.f, 0.f, 0.f);
        if (r < nrows) v = *(const float4*)(x + (size_t)(row0 + r) * D + 4 * kq);
        xs[r * 65 + 4 * kq + 0] = v.x;
        xs[r * 65 + 4 * kq + 1] = v.y;
        xs[r * 65 + 4 * kq + 2] = v.z;
        xs[r * 65 + 4 * kq + 3] = v.w;
    }
    __syncthreads();
    int ry = t >> 4, cx = t & 15;         // thread: rows 4ry..+3, cols 4cx..+3
    float acc[4][4] = {{0.f}};
    const float* xb = xs + (4 * ry) * 65;
#pragma unroll 8
    for (int k = 0; k < 64; ++k) {
        float4 wv = *(const float4*)(Ws + k * 64 + 4 * cx);
        float x0 = xb[k], x1 = xb[65 + k], x2 = xb[130 + k], x3 = xb[195 + k];
        acc[0][0] = fmaf(x0, wv.x, acc[0][0]); acc[0][1] = fmaf(x0, wv.y, acc[0][1]);
        acc[0][2] = fmaf(x0, wv.z, acc[0][2]); acc[0][3] = fmaf(x0, wv.w, acc[0][3]);
        acc[1][0] = fmaf(x1, wv.x, acc[1][0]); acc[1][1] = fmaf(x1, wv.y, acc[1][1]);
        acc[1][2] = fmaf(x1, wv.z, acc[1][2]); acc[1][3] = fmaf(x1, wv.w, acc[1][3]);
        acc[2][0] = fmaf(x2, wv.x, acc[2][0]); acc[2][1] = fmaf(x2, wv.y, acc[2][1]);
        acc[2][2] = fmaf(x2, wv.z, acc[2][2]); acc[2][3] = fmaf(x2, wv.w, acc[2][3]);
        acc[3][0] = fmaf(x3, wv.x, acc[3][0]); acc[3][1] = fmaf(x3, wv.y, acc[3][1]);
        acc[3][2] = fmaf(x3, wv.z, acc[3][2]); acc[3][3] = fmaf(x3, wv.w, acc[3][3]);
    }
    float4 a4 = *(const float4*)(att_src + 4 * cx);
#pragma unroll
    for (int j = 0; j < 4; ++j) {
        int r = 4 * ry + j;
        if (r < nrows) {
            ushort4 hv;
            hv.x = f2bf(acc[j][0]); hv.y = f2bf(acc[j][1]);
            hv.z = f2bf(acc[j][2]); hv.w = f2bf(acc[j][3]);
            *(ushort4*)(hb + (size_t)(row0 + r) * D + 4 * cx) = hv;
        }
        float p = acc[j][0] * a4.x + acc[j][1] * a4.y + acc[j][2] * a4.z + acc[j][3] * a4.w;
        p += __shfl_xor(p, 1, 64); p += __shfl_xor(p, 2, 64);
        p += __shfl_xor(p, 4, 64); p += __shfl_xor(p, 8, 64);
        if (cx == 0 && r < nrows) a_src[row0 + r] = p;
    }
}

// ---- K2: a_dst[i] = dot(x[res_n_id[i]], wad).  wave per dst ----
__global__ __launch_bounds__(256) void k_adst(const float* __restrict__ x,
                                              const int* __restrict__ res_n_id,
                                              const float* __restrict__ wad,
                                              float* __restrict__ a_dst) {
    int tid = threadIdx.x;
    int wid = blockIdx.x * 4 + (tid >> 6);
    int lane = tid & 63;
    if (wid >= N_DST) return;
    int row = res_n_id[wid];
    float p = x[(size_t)row * D + lane] * wad[lane];
#pragma unroll
    for (int off = 32; off; off >>= 1) p += __shfl_xor(p, off, 64);
    if (lane == 0) a_dst[wid] = p;
}

// ---- K3 (pass A): LDS-staged multi-split of edges into NBKT buckets ----
// record: meta = src(17b) | dst_lo4(4b)<<17 | bucket(11b)<<21 ; score f32
__global__ __launch_bounds__(256) void k_bucket(const int* __restrict__ es,
                                                const int* __restrict__ ed,
                                                const float* __restrict__ a_src,
                                                const float* __restrict__ a_dst,
                                                int* __restrict__ gcur,
                                                int2* __restrict__ buf) {
    __shared__ int  hist[NBKT];
    __shared__ int  lofs[NBKT];
    __shared__ int  gbase[NBKT];
    __shared__ int  part[256];
    __shared__ int2 stage[TILE];
    int t = threadIdx.x;
    int base = blockIdx.x * TILE;
    int nE = NE - base; if (nE > TILE) nE = TILE;

    for (int i = t; i < NBKT; i += 256) hist[i] = 0;
    __syncthreads();

    int s_[16]; int d_[16]; float v_[16];
#pragma unroll
    for (int j = 0; j < 16; ++j) {
        int i = t + 256 * j;
        d_[j] = -1;
        if (i < nE) {
            s_[j] = es[base + i];
            d_[j] = ed[base + i];
            atomicAdd(&hist[d_[j] >> 4], 1);
        }
    }
#pragma unroll
    for (int j = 0; j < 16; ++j) {
        if (d_[j] >= 0) {
            float v = a_src[s_[j]] + a_dst[d_[j]];
            v_[j] = v > 0.f ? v : NEG_SLOPE * v;
        }
    }
    __syncthreads();

    // exclusive scan of hist (5 buckets/thread * 250 threads = 1250)
    int c0 = t * 5;
    int sum = 0;
    if (c0 < NBKT) {
#pragma unroll
        for (int j = 0; j < 5; ++j) sum += hist[c0 + j];
    }
    part[t] = sum;
    __syncthreads();
    for (int off = 1; off < 256; off <<= 1) {
        int v = (t >= off) ? part[t - off] : 0;
        __syncthreads();
        part[t] += v;
        __syncthreads();
    }
    int run = (t == 0) ? 0 : part[t - 1];
    if (c0 < NBKT) {
#pragma unroll
        for (int j = 0; j < 5; ++j) {
            int b = c0 + j;
            int hc = hist[b];
            lofs[b] = run;
            gbase[b] = hc ? atomicAdd(&gcur[b], hc) : 0;
            run += hc;
        }
    }
    __syncthreads();
    for (int i = t; i < NBKT; i += 256) hist[i] = lofs[i];  // hist -> cursor
    __syncthreads();

#pragma unroll
    for (int j = 0; j < 16; ++j) {
        if (d_[j] >= 0) {
            int b = d_[j] >> 4;
            int p = atomicAdd(&hist[b], 1);
            int meta = s_[j] | ((d_[j] & 15) << 17) | (b << 21);
            stage[p] = make_int2(meta, __float_as_int(v_[j]));
        }
    }
    __syncthreads();

    for (int idx = t; idx < nE; idx += 256) {
        int2 rec = stage[idx];
        int b = ((unsigned)rec.x) >> 21;
        int gpos = gbase[b] + idx - lofs[b];
        if (gpos < (b + 1) * BCAP) buf[gpos] = rec;   // coalesced runs
    }
}

// ---- K4 (pass B): per-bucket softmax + aggregate into LDS, one out write ----
__global__ __launch_bounds__(256) void k_aggB(const int2* __restrict__ buf,
                                              const int* __restrict__ gcur,
                                              const unsigned short* __restrict__ hb,
                                              const float* __restrict__ bias,
                                              float* __restrict__ out) {
    __shared__ int2 recs[BCAP];          // 12 KB
    __shared__ float acc[16 * 64];       // 4 KB
    __shared__ unsigned mx[16];
    __shared__ float mxf[16];
    __shared__ float den[16];
    int b = blockIdx.x;
    int t = threadIdx.x;
    int n = gcur[b] - b * BCAP;
    if (n > BCAP) n = BCAP;

    for (int i = t; i < 16 * 64; i += 256) acc[i] = 0.f;
    if (t < 16) { mx[t] = ENC_NEG_INF; den[t] = 0.f; }
    for (int i = t; i < n; i += 256) recs[i] = buf[b * BCAP + i];
    __syncthreads();

    for (int i = t; i < n; i += 256) {
        int dlo = (recs[i].x >> 17) & 15;
        atomicMax(&mx[dlo], enc_f32(__int_as_float(recs[i].y)));
    }
    __syncthreads();
    if (t < 16) mxf[t] = dec_f32(mx[t]);
    __syncthreads();

    int w = t >> 6, lane = t & 63;
    int q = (n + 3) >> 2;
    int beg = w * q, end = beg + q; if (end > n) end = n;
    int i = beg;
    for (; i + 3 < end; i += 4) {
        int2 r0 = recs[i], r1 = recs[i + 1], r2 = recs[i + 2], r3 = recs[i + 3];
        int s0 = r0.x & 0x1FFFF, s1 = r1.x & 0x1FFFF, s2 = r2.x & 0x1FFFF, s3 = r3.x & 0x1FFFF;
        int p0 = ((r0.x >> 17) & 15) << 6, p1 = ((r1.x >> 17) & 15) << 6;
        int p2 = ((r2.x >> 17) & 15) << 6, p3 = ((r3.x >> 17) & 15) << 6;
        unsigned short g0 = hb[(size_t)s0 * D + lane];
        unsigned short g1 = hb[(size_t)s1 * D + lane];
        unsigned short g2 = hb[(size_t)s2 * D + lane];
        unsigned short g3 = hb[(size_t)s3 * D + lane];
        float e0 = __expf(__int_as_float(r0.y) - mxf[p0 >> 6]);
        float e1 = __expf(__int_as_float(r1.y) - mxf[p1 >> 6]);
        float e2 = __expf(__int_as_float(r2.y) - mxf[p2 >> 6]);
        float e3 = __expf(__int_as_float(r3.y) - mxf[p3 >> 6]);
        atomicAdd(&acc[p0 + lane], e0 * bf2f(g0));
        atomicAdd(&acc[p1 + lane], e1 * bf2f(g1));
        atomicAdd(&acc[p2 + lane], e2 * bf2f(g2));
        atomicAdd(&acc[p3 + lane], e3 * bf2f(g3));
        if (lane == 0) {
            atomicAdd(&den[p0 >> 6], e0); atomicAdd(&den[p1 >> 6], e1);
            atomicAdd(&den[p2 >> 6], e2); atomicAdd(&den[p3 >> 6], e3);
        }
    }
    for (; i < end; ++i) {
        int2 r = recs[i];
        int s = r.x & 0x1FFFF;
        int p = ((r.x >> 17) & 15) << 6;
        float e = __expf(__int_as_float(r.y) - mxf[p >> 6]);
        atomicAdd(&acc[p + lane], e * bf2f(hb[(size_t)s * D + lane]));
        if (lane == 0) atomicAdd(&den[p >> 6], e);
    }
    __syncthreads();

    for (int idx = t; idx < 16 * 64; idx += 256) {
        int dlo = idx >> 6, c = idx & 63;
        out[(size_t)(b * 16 + dlo) * D + c] = acc[idx] / (den[dlo] + 1e-16f) + bias[c];
    }
}

extern "C" void kernel_launch(void* const* d_in, const int* in_sizes, int n_in,
                              void* d_out, int out_size, void* d_ws, size_t ws_size,
                              hipStream_t stream) {
    const float* x        = (const float*)d_in[0];
    const int*   res_n_id = (const int*)d_in[1];
    const int*   edge_src = (const int*)d_in[2];
    const int*   edge_dst = (const int*)d_in[3];
    const float* W        = (const float*)d_in[4];
    const float* att_src  = (const float*)d_in[5];
    const float* att_dst  = (const float*)d_in[6];
    const float* bias     = (const float*)d_in[7];
    float* out = (float*)d_out;

    char* w = (char*)d_ws;
    unsigned short* hb = (unsigned short*)w; w += (size_t)N_SRC * D * 2;   // 12.8 MB
    int2*  buf   = (int2*)w;  w += (size_t)NBKT * BCAP * 8;                // 15.36 MB
    float* a_src = (float*)w; w += (size_t)N_SRC * 4;
    float* a_dst = (float*)w; w += (size_t)N_DST * 4;
    float* wad   = (float*)w; w += 256;
    int*   gcur  = (int*)w;   w += (size_t)NBKT * 4;

    k_wad_init<<<(NBKT + 255) / 256, 256, 0, stream>>>(W, att_dst, wad, gcur);
    k_h<<<(N_SRC + 63) / 64, 256, 0, stream>>>(x, W, att_src, hb, a_src);
    k_adst<<<N_DST / 4, 256, 0, stream>>>(x, res_n_id, wad, a_dst);
    k_bucket<<<(NE + TILE - 1) / TILE, 256, 0, stream>>>(edge_src, edge_dst, a_src, a_dst, gcur, buf);
    k_aggB<<<NBKT, 256, 0, stream>>>(buf, gcur, hb, bias, out);
}

// Round 4
// 212.912 us; speedup vs baseline: 2.8530x; 2.8530x over previous
//
#include <hip/hip_runtime.h>

#define N_SRC 100000
#define N_DST 20000
#define NE    1250000
#define D     64
#define NEG_SLOPE 0.2f

#define NBKT 1250      // buckets of 16 dsts: bucket = dst >> 4
#define BCAP 1536      // capacity per bucket (mean 1000, 17 sigma headroom)
#define TILE 4096      // edges per pass-A block

__device__ __forceinline__ unsigned short f2bf(float f) {
    unsigned u = __float_as_uint(f);
    u += 0x7FFFu + ((u >> 16) & 1);   // RNE
    return (unsigned short)(u >> 16);
}
__device__ __forceinline__ float bf2f(unsigned short b) {
    return __uint_as_float(((unsigned)b) << 16);
}

// ---- K0: wad[k] = W[k,:]@att_dst  +  init bucket cursors ----
__global__ void k_wad_init(const float* __restrict__ W,
                           const float* __restrict__ att_dst,
                           float* __restrict__ wad, int* __restrict__ gcur) {
    int g = blockIdx.x * 256 + threadIdx.x;
    if (g < NBKT) gcur[g] = g * BCAP;
    if (g < D) {
        float s = 0.f;
#pragma unroll
        for (int c = 0; c < D; ++c) s += W[g * D + c] * att_dst[c];
        wad[g] = s;
    }
}

// ---- K1: h = x @ W (bf16 out), a_src = h @ att_src.  64x64 tile, 4x4 reg ----
__global__ __launch_bounds__(256) void k_h(const float* __restrict__ x,
                                           const float* __restrict__ W,
                                           const float* __restrict__ att_src,
                                           unsigned short* __restrict__ hb,
                                           float* __restrict__ a_src) {
    __shared__ float xs[64 * 65];   // padded: bank-conflict-free row reads
    __shared__ float Ws[64 * 64];
    int t = threadIdx.x;
    int row0 = blockIdx.x * 64;
    int nrows = N_SRC - row0; if (nrows > 64) nrows = 64;
    {
        const float4* W4 = (const float4*)W;
        float4* Ws4 = (float4*)Ws;
#pragma unroll
        for (int p = 0; p < 4; ++p) Ws4[t + 256 * p] = W4[t + 256 * p];
    }
#pragma unroll
    for (int p = 0; p < 4; ++p) {
        int idx = t + 256 * p;            // 0..1023
        int r = idx >> 4, kq = idx & 15;
        float4 v = make_float4(0.f, 0.f, 0.f, 0.f);
        if (r < nrows) v = *(const float4*)(x + (size_t)(row0 + r) * D + 4 * kq);
        xs[r * 65 + 4 * kq + 0] = v.x;
        xs[r * 65 + 4 * kq + 1] = v.y;
        xs[r * 65 + 4 * kq + 2] = v.z;
        xs[r * 65 + 4 * kq + 3] = v.w;
    }
    __syncthreads();
    int ry = t >> 4, cx = t & 15;         // thread: rows 4ry..+3, cols 4cx..+3
    float acc[4][4] = {{0.f}};
    const float* xb = xs + (4 * ry) * 65;
#pragma unroll 8
    for (int k = 0; k < 64; ++k) {
        float4 wv = *(const float4*)(Ws + k * 64 + 4 * cx);
        float x0 = xb[k], x1 = xb[65 + k], x2 = xb[130 + k], x3 = xb[195 + k];
        acc[0][0] = fmaf(x0, wv.x, acc[0][0]); acc[0][1] = fmaf(x0, wv.y, acc[0][1]);
        acc[0][2] = fmaf(x0, wv.z, acc[0][2]); acc[0][3] = fmaf(x0, wv.w, acc[0][3]);
        acc[1][0] = fmaf(x1, wv.x, acc[1][0]); acc[1][1] = fmaf(x1, wv.y, acc[1][1]);
        acc[1][2] = fmaf(x1, wv.z, acc[1][2]); acc[1][3] = fmaf(x1, wv.w, acc[1][3]);
        acc[2][0] = fmaf(x2, wv.x, acc[2][0]); acc[2][1] = fmaf(x2, wv.y, acc[2][1]);
        acc[2][2] = fmaf(x2, wv.z, acc[2][2]); acc[2][3] = fmaf(x2, wv.w, acc[2][3]);
        acc[3][0] = fmaf(x3, wv.x, acc[3][0]); acc[3][1] = fmaf(x3, wv.y, acc[3][1]);
        acc[3][2] = fmaf(x3, wv.z, acc[3][2]); acc[3][3] = fmaf(x3, wv.w, acc[3][3]);
    }
    float4 a4 = *(const float4*)(att_src + 4 * cx);
#pragma unroll
    for (int j = 0; j < 4; ++j) {
        int r = 4 * ry + j;
        if (r < nrows) {
            ushort4 hv;
            hv.x = f2bf(acc[j][0]); hv.y = f2bf(acc[j][1]);
            hv.z = f2bf(acc[j][2]); hv.w = f2bf(acc[j][3]);
            *(ushort4*)(hb + (size_t)(row0 + r) * D + 4 * cx) = hv;
        }
        float p = acc[j][0] * a4.x + acc[j][1] * a4.y + acc[j][2] * a4.z + acc[j][3] * a4.w;
        p += __shfl_xor(p, 1, 64); p += __shfl_xor(p, 2, 64);
        p += __shfl_xor(p, 4, 64); p += __shfl_xor(p, 8, 64);
        if (cx == 0 && r < nrows) a_src[row0 + r] = p;
    }
}

// ---- K2: a_dst[i] = dot(x[res_n_id[i]], wad).  wave per dst ----
__global__ __launch_bounds__(256) void k_adst(const float* __restrict__ x,
                                              const int* __restrict__ res_n_id,
                                              const float* __restrict__ wad,
                                              float* __restrict__ a_dst) {
    int tid = threadIdx.x;
    int wid = blockIdx.x * 4 + (tid >> 6);
    int lane = tid & 63;
    if (wid >= N_DST) return;
    int row = res_n_id[wid];
    float p = x[(size_t)row * D + lane] * wad[lane];
#pragma unroll
    for (int off = 32; off; off >>= 1) p += __shfl_xor(p, off, 64);
    if (lane == 0) a_dst[wid] = p;
}

// ---- K3 (pass A): LDS-staged multi-split of edges into NBKT buckets ----
// record: meta = src(17b) | dst_lo4(4b)<<17 | bucket(11b)<<21 ; score f32
__global__ __launch_bounds__(256) void k_bucket(const int* __restrict__ es,
                                                const int* __restrict__ ed,
                                                const float* __restrict__ a_src,
                                                const float* __restrict__ a_dst,
                                                int* __restrict__ gcur,
                                                int2* __restrict__ buf) {
    __shared__ int  hist[NBKT];
    __shared__ int  lofs[NBKT];
    __shared__ int  gbase[NBKT];
    __shared__ int  part[256];
    __shared__ int2 stage[TILE];
    int t = threadIdx.x;
    int base = blockIdx.x * TILE;
    int nE = NE - base; if (nE > TILE) nE = TILE;

    for (int i = t; i < NBKT; i += 256) hist[i] = 0;
    __syncthreads();

    int s_[16]; int d_[16]; float v_[16];
#pragma unroll
    for (int j = 0; j < 16; ++j) {
        int i = t + 256 * j;
        d_[j] = -1;
        if (i < nE) {
            s_[j] = es[base + i];
            d_[j] = ed[base + i];
            atomicAdd(&hist[d_[j] >> 4], 1);
        }
    }
#pragma unroll
    for (int j = 0; j < 16; ++j) {
        if (d_[j] >= 0) {
            float v = a_src[s_[j]] + a_dst[d_[j]];
            v_[j] = v > 0.f ? v : NEG_SLOPE * v;
        }
    }
    __syncthreads();

    // exclusive scan of hist (5 buckets/thread * 250 threads = 1250)
    int c0 = t * 5;
    int sum = 0;
    if (c0 < NBKT) {
#pragma unroll
        for (int j = 0; j < 5; ++j) sum += hist[c0 + j];
    }
    part[t] = sum;
    __syncthreads();
    for (int off = 1; off < 256; off <<= 1) {
        int v = (t >= off) ? part[t - off] : 0;
        __syncthreads();
        part[t] += v;
        __syncthreads();
    }
    int run = (t == 0) ? 0 : part[t - 1];
    if (c0 < NBKT) {
#pragma unroll
        for (int j = 0; j < 5; ++j) {
            int b = c0 + j;
            int hc = hist[b];
            lofs[b] = run;
            gbase[b] = hc ? atomicAdd(&gcur[b], hc) : 0;
            run += hc;
        }
    }
    __syncthreads();
    for (int i = t; i < NBKT; i += 256) hist[i] = lofs[i];  // hist -> cursor
    __syncthreads();

#pragma unroll
    for (int j = 0; j < 16; ++j) {
        if (d_[j] >= 0) {
            int b = d_[j] >> 4;
            int p = atomicAdd(&hist[b], 1);
            int meta = s_[j] | ((d_[j] & 15) << 17) | (b << 21);
            stage[p] = make_int2(meta, __float_as_int(v_[j]));
        }
    }
    __syncthreads();

    for (int idx = t; idx < nE; idx += 256) {
        int2 rec = stage[idx];
        int b = ((unsigned)rec.x) >> 21;
        int gpos = gbase[b] + idx - lofs[b];
        if (gpos < (b + 1) * BCAP) buf[gpos] = rec;   // coalesced runs
    }
}

// ---- K4 (pass B): counting-sort bucket by dst_lo4 in LDS, then ----
// ---- 8 waves x 2 dsts register-accumulated softmax aggregate.   ----
__global__ __launch_bounds__(512) void k_aggB(const int2* __restrict__ buf,
                                              const int* __restrict__ gcur,
                                              const unsigned short* __restrict__ hb,
                                              const float* __restrict__ bias,
                                              float* __restrict__ out) {
    __shared__ int2 sorted[BCAP];    // 12 KB
    __shared__ int  scw[16 * 8];     // (bin, wave) counts -> inclusive scan
    __shared__ int  begs[17];
    int b = blockIdx.x;
    int t = threadIdx.x;
    int w = t >> 6, lane = t & 63;
    int n = gcur[b] - b * BCAP;
    if (n > BCAP) n = BCAP;
    if (n < 0) n = 0;

    // phase 1: load my <=3 records (interleaved = coalesced), register hist
    const int2* src = buf + (size_t)b * BCAP;
    int2 r0 = make_int2(0, 0), r1 = make_int2(0, 0), r2 = make_int2(0, 0);
    int bin0 = -1, bin1 = -1, bin2 = -1;
    if (t < n)        { r0 = src[t];        bin0 = (r0.x >> 17) & 15; }
    if (t + 512 < n)  { r1 = src[t + 512];  bin1 = (r1.x >> 17) & 15; }
    if (t + 1024 < n) { r2 = src[t + 1024]; bin2 = (r2.x >> 17) & 15; }

    int h[16], incl[16];
#pragma unroll
    for (int i = 0; i < 16; ++i)
        h[i] = (bin0 == i) + (bin1 == i) + (bin2 == i);

    // phase 2a: per-bin inclusive shuffle-scan across the wave
#pragma unroll
    for (int i = 0; i < 16; ++i) {
        int v = h[i];
#pragma unroll
        for (int off = 1; off < 64; off <<= 1) {
            int u = __shfl_up(v, off, 64);
            if (lane >= off) v += u;
        }
        incl[i] = v;
        int tot = __shfl(v, 63, 64);
        if (lane == 0) scw[i * 8 + w] = tot;
    }
    __syncthreads();

    // phase 2b: inclusive block scan over scw[128] (bin-major, wave-minor)
    for (int off = 1; off < 128; off <<= 1) {
        int up = 0;
        if (t < 128 && t >= off) up = scw[t - off];
        __syncthreads();
        if (t < 128 && t >= off) scw[t] += up;
        __syncthreads();
    }
    if (t < 16) begs[t] = (t == 0) ? 0 : scw[t * 8 - 1];
    if (t == 16) begs[16] = n;

    // phase 3: place records
    int p0 = 0, p1 = 0, p2 = 0;
#pragma unroll
    for (int i = 0; i < 16; ++i) {
        int idx = i * 8 + w;
        int base_i = ((idx ? scw[idx - 1] : 0)) + (incl[i] - h[i]);
        p0 += (bin0 == i) ? base_i : 0;
        p1 += (bin1 == i) ? base_i : 0;
        p2 += (bin2 == i) ? base_i : 0;
    }
    p1 += (bin1 == bin0);
    p2 += (bin2 == bin0) + (bin2 == bin1);
    if (bin0 >= 0) sorted[p0] = r0;
    if (bin1 >= 0) sorted[p1] = r1;
    if (bin2 >= 0) sorted[p2] = r2;
    __syncthreads();

    // phase 4: wave w handles dsts 2w, 2w+1; register softmax-aggregate
    float bsv = bias[lane];
#pragma unroll
    for (int q = 0; q < 2; ++q) {
        int dlo = w * 2 + q;
        int beg = begs[dlo], end = begs[dlo + 1];
        float mx = -1e30f;
        for (int i = beg + lane; i < end; i += 64)
            mx = fmaxf(mx, __int_as_float(sorted[i].y));
#pragma unroll
        for (int off = 32; off; off >>= 1) mx = fmaxf(mx, __shfl_xor(mx, off, 64));

        float acc = 0.f, den = 0.f;
        int i = beg;
        for (; i + 3 < end; i += 4) {
            int2 e0 = sorted[i], e1 = sorted[i + 1], e2 = sorted[i + 2], e3 = sorted[i + 3];
            unsigned short g0 = hb[(size_t)(e0.x & 0x1FFFF) * D + lane];
            unsigned short g1 = hb[(size_t)(e1.x & 0x1FFFF) * D + lane];
            unsigned short g2 = hb[(size_t)(e2.x & 0x1FFFF) * D + lane];
            unsigned short g3 = hb[(size_t)(e3.x & 0x1FFFF) * D + lane];
            float w0 = __expf(__int_as_float(e0.y) - mx);
            float w1 = __expf(__int_as_float(e1.y) - mx);
            float w2 = __expf(__int_as_float(e2.y) - mx);
            float w3 = __expf(__int_as_float(e3.y) - mx);
            acc = fmaf(w0, bf2f(g0), acc); acc = fmaf(w1, bf2f(g1), acc);
            acc = fmaf(w2, bf2f(g2), acc); acc = fmaf(w3, bf2f(g3), acc);
            den += (w0 + w1) + (w2 + w3);
        }
        for (; i < end; ++i) {
            int2 e = sorted[i];
            float we = __expf(__int_as_float(e.y) - mx);
            acc = fmaf(we, bf2f(hb[(size_t)(e.x & 0x1FFFF) * D + lane]), acc);
            den += we;
        }
        out[((size_t)b * 16 + dlo) * D + lane] = acc / (den + 1e-16f) + bsv;
    }
}

extern "C" void kernel_launch(void* const* d_in, const int* in_sizes, int n_in,
                              void* d_out, int out_size, void* d_ws, size_t ws_size,
                              hipStream_t stream) {
    const float* x        = (const float*)d_in[0];
    const int*   res_n_id = (const int*)d_in[1];
    const int*   edge_src = (const int*)d_in[2];
    const int*   edge_dst = (const int*)d_in[3];
    const float* W        = (const float*)d_in[4];
    const float* att_src  = (const float*)d_in[5];
    const float* att_dst  = (const float*)d_in[6];
    const float* bias     = (const float*)d_in[7];
    float* out = (float*)d_out;

    char* w = (char*)d_ws;
    unsigned short* hb = (unsigned short*)w; w += (size_t)N_SRC * D * 2;   // 12.8 MB
    int2*  buf   = (int2*)w;  w += (size_t)NBKT * BCAP * 8;                // 15.36 MB
    float* a_src = (float*)w; w += (size_t)N_SRC * 4;
    float* a_dst = (float*)w; w += (size_t)N_DST * 4;
    float* wad   = (float*)w; w += 256;
    int*   gcur  = (int*)w;   w += (size_t)NBKT * 4;

    k_wad_init<<<(NBKT + 255) / 256, 256, 0, stream>>>(W, att_dst, wad, gcur);
    k_h<<<(N_SRC + 63) / 64, 256, 0, stream>>>(x, W, att_src, hb, a_src);
    k_adst<<<N_DST / 4, 256, 0, stream>>>(x, res_n_id, wad, a_dst);
    k_bucket<<<(NE + TILE - 1) / TILE, 256, 0, stream>>>(edge_src, edge_dst, a_src, a_dst, gcur, buf);
    k_aggB<<<NBKT, 512, 0, stream>>>(buf, gcur, hb, bias, out);
}

// Round 5
// 197.578 us; speedup vs baseline: 3.0744x; 1.0776x over previous
//
#include <hip/hip_runtime.h>

#define N_SRC 100000
#define N_DST 20000
#define NE    1250000
#define D     64
#define NEG_SLOPE 0.2f

#define NBKT 1250      // buckets of 16 dsts: bucket = dst >> 4
#define BCAP 1536      // capacity per bucket (mean 1000, ~17 sigma headroom)
#define TILE 4096      // edges per pass-A block

__device__ __forceinline__ unsigned short f2bf(float f) {
    unsigned u = __float_as_uint(f);
    u += 0x7FFFu + ((u >> 16) & 1);   // RNE
    return (unsigned short)(u >> 16);
}
__device__ __forceinline__ float bf2f(unsigned short b) {
    return __uint_as_float(((unsigned)b) << 16);
}

// ---- K0: wad[k] = W[k,:]@att_dst  +  init bucket cursors ----
__global__ void k_wad_init(const float* __restrict__ W,
                           const float* __restrict__ att_dst,
                           float* __restrict__ wad, int* __restrict__ gcur) {
    int g = blockIdx.x * 256 + threadIdx.x;
    if (g < NBKT) gcur[g] = g * BCAP;
    if (g < D) {
        float s = 0.f;
#pragma unroll
        for (int c = 0; c < D; ++c) s += W[g * D + c] * att_dst[c];
        wad[g] = s;
    }
}

// ---- K1: h = x @ W (bf16 out), a_src = h @ att_src. ----
// 64x64 tile, 4x4 reg; x-tile stored k-major so inner loop is 2x ds_read_b128.
__global__ __launch_bounds__(256) void k_h(const float* __restrict__ x,
                                           const float* __restrict__ W,
                                           const float* __restrict__ att_src,
                                           unsigned short* __restrict__ hb,
                                           float* __restrict__ a_src) {
    __shared__ float xs[64 * 68];   // xs[k*68 + r] = x[row0+r][k]
    __shared__ float Ws[64 * 64];
    int t = threadIdx.x;
    int row0 = blockIdx.x * 64;
    int nrows = N_SRC - row0; if (nrows > 64) nrows = 64;
    {
        const float4* W4 = (const float4*)W;
        float4* Ws4 = (float4*)Ws;
#pragma unroll
        for (int p = 0; p < 4; ++p) Ws4[t + 256 * p] = W4[t + 256 * p];
    }
#pragma unroll
    for (int p = 0; p < 4; ++p) {
        int idx = t + 256 * p;            // 0..1023
        int r = idx >> 4, kq = idx & 15;
        float4 v = make_float4(0.f, 0.f, 0.f, 0.f);
        if (r < nrows) v = *(const float4*)(x + (size_t)(row0 + r) * D + 4 * kq);
        xs[(4 * kq + 0) * 68 + r] = v.x;
        xs[(4 * kq + 1) * 68 + r] = v.y;
        xs[(4 * kq + 2) * 68 + r] = v.z;
        xs[(4 * kq + 3) * 68 + r] = v.w;
    }
    __syncthreads();
    int ry = t >> 4, cx = t & 15;         // thread: rows 4ry..+3, cols 4cx..+3
    float acc[4][4] = {{0.f}};
#pragma unroll 8
    for (int k = 0; k < 64; ++k) {
        float4 xv = *(const float4*)(xs + k * 68 + 4 * ry);
        float4 wv = *(const float4*)(Ws + k * 64 + 4 * cx);
        acc[0][0] = fmaf(xv.x, wv.x, acc[0][0]); acc[0][1] = fmaf(xv.x, wv.y, acc[0][1]);
        acc[0][2] = fmaf(xv.x, wv.z, acc[0][2]); acc[0][3] = fmaf(xv.x, wv.w, acc[0][3]);
        acc[1][0] = fmaf(xv.y, wv.x, acc[1][0]); acc[1][1] = fmaf(xv.y, wv.y, acc[1][1]);
        acc[1][2] = fmaf(xv.y, wv.z, acc[1][2]); acc[1][3] = fmaf(xv.y, wv.w, acc[1][3]);
        acc[2][0] = fmaf(xv.z, wv.x, acc[2][0]); acc[2][1] = fmaf(xv.z, wv.y, acc[2][1]);
        acc[2][2] = fmaf(xv.z, wv.z, acc[2][2]); acc[2][3] = fmaf(xv.z, wv.w, acc[2][3]);
        acc[3][0] = fmaf(xv.w, wv.x, acc[3][0]); acc[3][1] = fmaf(xv.w, wv.y, acc[3][1]);
        acc[3][2] = fmaf(xv.w, wv.z, acc[3][2]); acc[3][3] = fmaf(xv.w, wv.w, acc[3][3]);
    }
    float4 a4 = *(const float4*)(att_src + 4 * cx);
#pragma unroll
    for (int j = 0; j < 4; ++j) {
        int r = 4 * ry + j;
        if (r < nrows) {
            ushort4 hv;
            hv.x = f2bf(acc[j][0]); hv.y = f2bf(acc[j][1]);
            hv.z = f2bf(acc[j][2]); hv.w = f2bf(acc[j][3]);
            *(ushort4*)(hb + (size_t)(row0 + r) * D + 4 * cx) = hv;
        }
        float p = acc[j][0] * a4.x + acc[j][1] * a4.y + acc[j][2] * a4.z + acc[j][3] * a4.w;
        p += __shfl_xor(p, 1, 64); p += __shfl_xor(p, 2, 64);
        p += __shfl_xor(p, 4, 64); p += __shfl_xor(p, 8, 64);
        if (cx == 0 && r < nrows) a_src[row0 + r] = p;
    }
}

// ---- K2: a_dst[i] = dot(x[res_n_id[i]], wad).  wave per dst ----
__global__ __launch_bounds__(256) void k_adst(const float* __restrict__ x,
                                              const int* __restrict__ res_n_id,
                                              const float* __restrict__ wad,
                                              float* __restrict__ a_dst) {
    int tid = threadIdx.x;
    int wid = blockIdx.x * 4 + (tid >> 6);
    int lane = tid & 63;
    if (wid >= N_DST) return;
    int row = res_n_id[wid];
    float p = x[(size_t)row * D + lane] * wad[lane];
#pragma unroll
    for (int off = 32; off; off >>= 1) p += __shfl_xor(p, off, 64);
    if (lane == 0) a_dst[wid] = p;
}

// ---- K3 (pass A): LDS-staged multi-split of edges into NBKT buckets ----
// record: meta = src(17b) | dst_lo4(4b)<<17 | bucket(11b)<<21 ; score f32
// rank within (block,bucket) captured from the histogram atomic itself.
__global__ __launch_bounds__(256) void k_bucket(const int* __restrict__ es,
                                                const int* __restrict__ ed,
                                                const float* __restrict__ a_src,
                                                const float* __restrict__ a_dst,
                                                int* __restrict__ gcur,
                                                int2* __restrict__ buf) {
    __shared__ int  hist[NBKT];
    __shared__ int  lofs[NBKT];
    __shared__ int  gbase[NBKT];
    __shared__ int  wtot[4];
    __shared__ int2 stage[TILE];
    int t = threadIdx.x;
    int w = t >> 6, lane = t & 63;
    int base = blockIdx.x * TILE;
    int nE = NE - base; if (nE > TILE) nE = TILE;

    for (int i = t; i < NBKT; i += 256) hist[i] = 0;
    __syncthreads();

    int s_[16], d_[16], rk_[16]; float v_[16];
#pragma unroll
    for (int j = 0; j < 16; ++j) {
        int i = t + 256 * j;
        d_[j] = -1;
        if (i < nE) {
            s_[j] = es[base + i];
            d_[j] = ed[base + i];
            rk_[j] = atomicAdd(&hist[d_[j] >> 4], 1);   // rank within bucket
        }
    }
#pragma unroll
    for (int j = 0; j < 16; ++j) {
        if (d_[j] >= 0) {
            float v = a_src[s_[j]] + a_dst[d_[j]];
            v_[j] = v > 0.f ? v : NEG_SLOPE * v;
        }
    }
    __syncthreads();

    // exclusive scan of hist: 5 buckets/thread, wave shuffle-scan, 4-way combine
    int c0 = t * 5;
    int sum = 0;
    if (c0 < NBKT) {
#pragma unroll
        for (int j = 0; j < 5; ++j) sum += hist[c0 + j];
    }
    int incl = sum;
#pragma unroll
    for (int off = 1; off < 64; off <<= 1) {
        int u = __shfl_up(incl, off, 64);
        if (lane >= off) incl += u;
    }
    if (lane == 63) wtot[w] = incl;
    __syncthreads();
    int wpre = 0;
#pragma unroll
    for (int j = 0; j < 4; ++j) wpre += (j < w) ? wtot[j] : 0;
    if (c0 < NBKT) {
        int run = wpre + incl - sum;
#pragma unroll
        for (int j = 0; j < 5; ++j) {
            int b = c0 + j;
            int hc = hist[b];
            lofs[b] = run;
            gbase[b] = hc ? atomicAdd(&gcur[b], hc) : 0;
            run += hc;
        }
    }
    __syncthreads();

#pragma unroll
    for (int j = 0; j < 16; ++j) {
        if (d_[j] >= 0) {
            int b = d_[j] >> 4;
            int meta = s_[j] | ((d_[j] & 15) << 17) | (b << 21);
            stage[lofs[b] + rk_[j]] = make_int2(meta, __float_as_int(v_[j]));
        }
    }
    __syncthreads();

    for (int idx = t; idx < nE; idx += 256) {
        int2 rec = stage[idx];
        int b = ((unsigned)rec.x) >> 21;
        int gpos = gbase[b] + idx - lofs[b];
        if (gpos < (b + 1) * BCAP) buf[gpos] = rec;   // coalesced runs
    }
}

// ---- K4 (pass B): counting-sort bucket by dst_lo4 in LDS, then ----
// 8 waves x 2 dsts; 4 records/wave-iteration, ushort4 gathers (16 lanes/rec).
__global__ __launch_bounds__(512) void k_aggB(const int2* __restrict__ buf,
                                              const int* __restrict__ gcur,
                                              const unsigned short* __restrict__ hb,
                                              const float* __restrict__ bias,
                                              float* __restrict__ out) {
    __shared__ int2 sorted[BCAP];    // 12 KB
    __shared__ int  scw[16 * 8];     // (bin, wave) counts -> inclusive scan
    __shared__ int  begs[17];
    int b = blockIdx.x;
    int t = threadIdx.x;
    int w = t >> 6, lane = t & 63;
    int n = gcur[b] - b * BCAP;
    if (n > BCAP) n = BCAP;
    if (n < 0) n = 0;

    // phase 1: load my <=3 records (interleaved = coalesced), register hist
    const int2* src = buf + (size_t)b * BCAP;
    int2 r0 = make_int2(0, 0), r1 = make_int2(0, 0), r2 = make_int2(0, 0);
    int bin0 = -1, bin1 = -1, bin2 = -1;
    if (t < n)        { r0 = src[t];        bin0 = (r0.x >> 17) & 15; }
    if (t + 512 < n)  { r1 = src[t + 512];  bin1 = (r1.x >> 17) & 15; }
    if (t + 1024 < n) { r2 = src[t + 1024]; bin2 = (r2.x >> 17) & 15; }

    int h[16], incl[16];
#pragma unroll
    for (int i = 0; i < 16; ++i)
        h[i] = (bin0 == i) + (bin1 == i) + (bin2 == i);

    // phase 2a: per-bin inclusive shuffle-scan across the wave
#pragma unroll
    for (int i = 0; i < 16; ++i) {
        int v = h[i];
#pragma unroll
        for (int off = 1; off < 64; off <<= 1) {
            int u = __shfl_up(v, off, 64);
            if (lane >= off) v += u;
        }
        incl[i] = v;
        int tot = __shfl(v, 63, 64);
        if (lane == 0) scw[i * 8 + w] = tot;
    }
    __syncthreads();

    // phase 2b: inclusive block scan over scw[128] (bin-major, wave-minor)
    for (int off = 1; off < 128; off <<= 1) {
        int up = 0;
        if (t < 128 && t >= off) up = scw[t - off];
        __syncthreads();
        if (t < 128 && t >= off) scw[t] += up;
        __syncthreads();
    }
    if (t < 16) begs[t] = (t == 0) ? 0 : scw[t * 8 - 1];
    if (t == 16) begs[16] = n;

    // phase 3: place records
    int p0 = 0, p1 = 0, p2 = 0;
#pragma unroll
    for (int i = 0; i < 16; ++i) {
        int idx = i * 8 + w;
        int base_i = ((idx ? scw[idx - 1] : 0)) + (incl[i] - h[i]);
        p0 += (bin0 == i) ? base_i : 0;
        p1 += (bin1 == i) ? base_i : 0;
        p2 += (bin2 == i) ? base_i : 0;
    }
    p1 += (bin1 == bin0);
    p2 += (bin2 == bin0) + (bin2 == bin1);
    if (bin0 >= 0) sorted[p0] = r0;
    if (bin1 >= 0) sorted[p1] = r1;
    if (bin2 >= 0) sorted[p2] = r2;
    __syncthreads();

    // phase 4: wave w handles dsts 2w, 2w+1.
    // 16-lane groups: group g handles record i+g, lane loads ushort4 (4 chans).
    int g = lane >> 4, il = lane & 15;
    float4 b4 = *(const float4*)(bias + 4 * il);
#pragma unroll
    for (int q = 0; q < 2; ++q) {
        int dlo = w * 2 + q;
        int beg = begs[dlo], end = begs[dlo + 1];
        float mx = -1e30f;
        for (int i = beg + lane; i < end; i += 64)
            mx = fmaxf(mx, __int_as_float(sorted[i].y));
#pragma unroll
        for (int off = 32; off; off >>= 1) mx = fmaxf(mx, __shfl_xor(mx, off, 64));

        float4 acc = make_float4(0.f, 0.f, 0.f, 0.f);
        float den = 0.f;
        int i = beg;
        for (; i + 8 <= end; i += 8) {       // no guards needed in main loop
            int2 ra = sorted[i + g];
            int2 rb = sorted[i + 4 + g];
            int sa = ra.x & 0x1FFFF, sb = rb.x & 0x1FFFF;
            ushort4 ha = *(const ushort4*)(hb + (size_t)sa * D + 4 * il);
            ushort4 hc = *(const ushort4*)(hb + (size_t)sb * D + 4 * il);
            float ea = __expf(__int_as_float(ra.y) - mx);
            float eb = __expf(__int_as_float(rb.y) - mx);
            acc.x = fmaf(ea, bf2f(ha.x), acc.x); acc.y = fmaf(ea, bf2f(ha.y), acc.y);
            acc.z = fmaf(ea, bf2f(ha.z), acc.z); acc.w = fmaf(ea, bf2f(ha.w), acc.w);
            acc.x = fmaf(eb, bf2f(hc.x), acc.x); acc.y = fmaf(eb, bf2f(hc.y), acc.y);
            acc.z = fmaf(eb, bf2f(hc.z), acc.z); acc.w = fmaf(eb, bf2f(hc.w), acc.w);
            den += ea + eb;
        }
        for (; i < end; i += 4) {            // guarded tail
            int idx = i + g;
            bool ok = idx < end;
            int2 r = ok ? sorted[idx] : make_int2(0, 0);
            float e = ok ? __expf(__int_as_float(r.y) - mx) : 0.f;
            if (ok) {
                int s = r.x & 0x1FFFF;
                ushort4 hv = *(const ushort4*)(hb + (size_t)s * D + 4 * il);
                acc.x = fmaf(e, bf2f(hv.x), acc.x); acc.y = fmaf(e, bf2f(hv.y), acc.y);
                acc.z = fmaf(e, bf2f(hv.z), acc.z); acc.w = fmaf(e, bf2f(hv.w), acc.w);
            }
            den += e;
        }
        // combine the 4 record-groups: xor16 (g0<->g1, g2<->g3), xor32
        acc.x += __shfl_xor(acc.x, 16, 64); acc.y += __shfl_xor(acc.y, 16, 64);
        acc.z += __shfl_xor(acc.z, 16, 64); acc.w += __shfl_xor(acc.w, 16, 64);
        acc.x += __shfl_xor(acc.x, 32, 64); acc.y += __shfl_xor(acc.y, 32, 64);
        acc.z += __shfl_xor(acc.z, 32, 64); acc.w += __shfl_xor(acc.w, 32, 64);
        den += __shfl_xor(den, 16, 64);
        den += __shfl_xor(den, 32, 64);
        if (g == 0) {
            float inv = 1.f / (den + 1e-16f);
            float4 o;
            o.x = acc.x * inv + b4.x; o.y = acc.y * inv + b4.y;
            o.z = acc.z * inv + b4.z; o.w = acc.w * inv + b4.w;
            *(float4*)(out + ((size_t)b * 16 + dlo) * D + 4 * il) = o;
        }
    }
}

extern "C" void kernel_launch(void* const* d_in, const int* in_sizes, int n_in,
                              void* d_out, int out_size, void* d_ws, size_t ws_size,
                              hipStream_t stream) {
    const float* x        = (const float*)d_in[0];
    const int*   res_n_id = (const int*)d_in[1];
    const int*   edge_src = (const int*)d_in[2];
    const int*   edge_dst = (const int*)d_in[3];
    const float* W        = (const float*)d_in[4];
    const float* att_src  = (const float*)d_in[5];
    const float* att_dst  = (const float*)d_in[6];
    const float* bias     = (const float*)d_in[7];
    float* out = (float*)d_out;

    char* w = (char*)d_ws;
    unsigned short* hb = (unsigned short*)w; w += (size_t)N_SRC * D * 2;   // 12.8 MB
    int2*  buf   = (int2*)w;  w += (size_t)NBKT * BCAP * 8;                // 15.36 MB
    float* a_src = (float*)w; w += (size_t)N_SRC * 4;
    float* a_dst = (float*)w; w += (size_t)N_DST * 4;
    float* wad   = (float*)w; w += 256;
    int*   gcur  = (int*)w;   w += (size_t)NBKT * 4;

    k_wad_init<<<(NBKT + 255) / 256, 256, 0, stream>>>(W, att_dst, wad, gcur);
    k_h<<<(N_SRC + 63) / 64, 256, 0, stream>>>(x, W, att_src, hb, a_src);
    k_adst<<<N_DST / 4, 256, 0, stream>>>(x, res_n_id, wad, a_dst);
    k_bucket<<<(NE + TILE - 1) / TILE, 256, 0, stream>>>(edge_src, edge_dst, a_src, a_dst, gcur, buf);
    k_aggB<<<NBKT, 512, 0, stream>>>(buf, gcur, hb, bias, out);
}

// Round 6
// 168.325 us; speedup vs baseline: 3.6087x; 1.1738x over previous
//
#include <hip/hip_runtime.h>

#define N_SRC 100000
#define N_DST 20000
#define NE    1250000
#define D     64
#define NEG_SLOPE 0.2f

#define NBKT 1250      // buckets of 16 dsts: bucket = dst >> 4
#define BCAP 1536      // capacity per bucket (mean 1000, ~17 sigma headroom)
#define TILE 4096      // edges per pass-A block

__device__ __forceinline__ unsigned short f2bf(float f) {
    unsigned u = __float_as_uint(f);
    u += 0x7FFFu + ((u >> 16) & 1);   // RNE
    return (unsigned short)(u >> 16);
}
__device__ __forceinline__ float blo(unsigned u) { return __uint_as_float(u << 16); }
__device__ __forceinline__ float bhi(unsigned u) { return __uint_as_float(u & 0xFFFF0000u); }

// ---- K0: wad[k] = W[k,:]@att_dst  +  init bucket cursors ----
__global__ void k_wad_init(const float* __restrict__ W,
                           const float* __restrict__ att_dst,
                           float* __restrict__ wad, int* __restrict__ gcur) {
    int g = blockIdx.x * 256 + threadIdx.x;
    if (g < NBKT) gcur[g] = g * BCAP;
    if (g < D) {
        float s = 0.f;
#pragma unroll
        for (int c = 0; c < D; ++c) s += W[g * D + c] * att_dst[c];
        wad[g] = s;
    }
}

// ---- K1: h = x @ W (bf16 out), a_src = h @ att_src. ----
// 64x64 tile, 4x4 reg; x-tile stored k-major so inner loop is 2x ds_read_b128.
__global__ __launch_bounds__(256) void k_h(const float* __restrict__ x,
                                           const float* __restrict__ W,
                                           const float* __restrict__ att_src,
                                           unsigned short* __restrict__ hb,
                                           float* __restrict__ a_src) {
    __shared__ float xs[64 * 68];   // xs[k*68 + r] = x[row0+r][k]
    __shared__ float Ws[64 * 64];
    int t = threadIdx.x;
    int row0 = blockIdx.x * 64;
    int nrows = N_SRC - row0; if (nrows > 64) nrows = 64;
    {
        const float4* W4 = (const float4*)W;
        float4* Ws4 = (float4*)Ws;
#pragma unroll
        for (int p = 0; p < 4; ++p) Ws4[t + 256 * p] = W4[t + 256 * p];
    }
#pragma unroll
    for (int p = 0; p < 4; ++p) {
        int idx = t + 256 * p;            // 0..1023
        int r = idx >> 4, kq = idx & 15;
        float4 v = make_float4(0.f, 0.f, 0.f, 0.f);
        if (r < nrows) v = *(const float4*)(x + (size_t)(row0 + r) * D + 4 * kq);
        xs[(4 * kq + 0) * 68 + r] = v.x;
        xs[(4 * kq + 1) * 68 + r] = v.y;
        xs[(4 * kq + 2) * 68 + r] = v.z;
        xs[(4 * kq + 3) * 68 + r] = v.w;
    }
    __syncthreads();
    int ry = t >> 4, cx = t & 15;         // thread: rows 4ry..+3, cols 4cx..+3
    float acc[4][4] = {{0.f}};
#pragma unroll 8
    for (int k = 0; k < 64; ++k) {
        float4 xv = *(const float4*)(xs + k * 68 + 4 * ry);
        float4 wv = *(const float4*)(Ws + k * 64 + 4 * cx);
        acc[0][0] = fmaf(xv.x, wv.x, acc[0][0]); acc[0][1] = fmaf(xv.x, wv.y, acc[0][1]);
        acc[0][2] = fmaf(xv.x, wv.z, acc[0][2]); acc[0][3] = fmaf(xv.x, wv.w, acc[0][3]);
        acc[1][0] = fmaf(xv.y, wv.x, acc[1][0]); acc[1][1] = fmaf(xv.y, wv.y, acc[1][1]);
        acc[1][2] = fmaf(xv.y, wv.z, acc[1][2]); acc[1][3] = fmaf(xv.y, wv.w, acc[1][3]);
        acc[2][0] = fmaf(xv.z, wv.x, acc[2][0]); acc[2][1] = fmaf(xv.z, wv.y, acc[2][1]);
        acc[2][2] = fmaf(xv.z, wv.z, acc[2][2]); acc[2][3] = fmaf(xv.z, wv.w, acc[2][3]);
        acc[3][0] = fmaf(xv.w, wv.x, acc[3][0]); acc[3][1] = fmaf(xv.w, wv.y, acc[3][1]);
        acc[3][2] = fmaf(xv.w, wv.z, acc[3][2]); acc[3][3] = fmaf(xv.w, wv.w, acc[3][3]);
    }
    float4 a4 = *(const float4*)(att_src + 4 * cx);
#pragma unroll
    for (int j = 0; j < 4; ++j) {
        int r = 4 * ry + j;
        if (r < nrows) {
            ushort4 hv;
            hv.x = f2bf(acc[j][0]); hv.y = f2bf(acc[j][1]);
            hv.z = f2bf(acc[j][2]); hv.w = f2bf(acc[j][3]);
            *(ushort4*)(hb + (size_t)(row0 + r) * D + 4 * cx) = hv;
        }
        float p = acc[j][0] * a4.x + acc[j][1] * a4.y + acc[j][2] * a4.z + acc[j][3] * a4.w;
        p += __shfl_xor(p, 1, 64); p += __shfl_xor(p, 2, 64);
        p += __shfl_xor(p, 4, 64); p += __shfl_xor(p, 8, 64);
        if (cx == 0 && r < nrows) a_src[row0 + r] = p;
    }
}

// ---- K2: a_dst[i] = dot(x[res_n_id[i]], wad).  wave per dst ----
__global__ __launch_bounds__(256) void k_adst(const float* __restrict__ x,
                                              const int* __restrict__ res_n_id,
                                              const float* __restrict__ wad,
                                              float* __restrict__ a_dst) {
    int tid = threadIdx.x;
    int wid = blockIdx.x * 4 + (tid >> 6);
    int lane = tid & 63;
    if (wid >= N_DST) return;
    int row = res_n_id[wid];
    float p = x[(size_t)row * D + lane] * wad[lane];
#pragma unroll
    for (int off = 32; off; off >>= 1) p += __shfl_xor(p, off, 64);
    if (lane == 0) a_dst[wid] = p;
}

// ---- K3 (pass A): LDS-staged multi-split of edges into NBKT buckets ----
// record int: src(17b) | dst_lo4(4b)<<17 | bucket(11b)<<21  (exactly 32 bits)
// 1024 threads for occupancy; no score computation here.
__global__ __launch_bounds__(1024) void k_bucket(const int* __restrict__ es,
                                                 const int* __restrict__ ed,
                                                 int* __restrict__ gcur,
                                                 int* __restrict__ buf) {
    __shared__ int hist[NBKT];
    __shared__ int lofs[NBKT];
    __shared__ int gbase[NBKT];
    __shared__ int wtot[16];
    __shared__ int stage[TILE];
    int t = threadIdx.x;
    int w = t >> 6, lane = t & 63;
    int base = blockIdx.x * TILE;
    int nE = NE - base; if (nE > TILE) nE = TILE;

    for (int i = t; i < NBKT; i += 1024) hist[i] = 0;
    __syncthreads();

    int s_[4], d_[4], rk_[4];
#pragma unroll
    for (int j = 0; j < 4; ++j) {
        int i = t + 1024 * j;
        d_[j] = -1;
        if (i < nE) {
            s_[j] = es[base + i];
            d_[j] = ed[base + i];
            rk_[j] = atomicAdd(&hist[d_[j] >> 4], 1);   // rank within bucket
        }
    }
    __syncthreads();

    // exclusive scan of hist: 2 buckets/thread (1250/2=625 threads active)
    int c0 = t * 2;
    int h0 = 0, h1 = 0;
    if (c0 < NBKT) { h0 = hist[c0]; h1 = hist[c0 + 1]; }
    int sum = h0 + h1;
    int incl = sum;
#pragma unroll
    for (int off = 1; off < 64; off <<= 1) {
        int u = __shfl_up(incl, off, 64);
        if (lane >= off) incl += u;
    }
    if (lane == 63) wtot[w] = incl;
    __syncthreads();
    int wpre = 0;
#pragma unroll
    for (int j = 0; j < 16; ++j) wpre += (j < w) ? wtot[j] : 0;
    if (c0 < NBKT) {
        int run = wpre + incl - sum;
        lofs[c0] = run;
        gbase[c0] = h0 ? atomicAdd(&gcur[c0], h0) : 0;
        run += h0;
        lofs[c0 + 1] = run;
        gbase[c0 + 1] = h1 ? atomicAdd(&gcur[c0 + 1], h1) : 0;
    }
    __syncthreads();

#pragma unroll
    for (int j = 0; j < 4; ++j) {
        if (d_[j] >= 0) {
            int b = d_[j] >> 4;
            stage[lofs[b] + rk_[j]] = s_[j] | ((d_[j] & 15) << 17) | (b << 21);
        }
    }
    __syncthreads();

    for (int idx = t; idx < nE; idx += 1024) {
        int rec = stage[idx];
        int b = ((unsigned)rec) >> 21;
        int gpos = gbase[b] + idx - lofs[b];
        if (gpos < (b + 1) * BCAP) buf[gpos] = rec;   // coalesced runs
    }
}

// ---- K4 (pass B): counting-sort bucket by dst_lo4 in LDS; compute scores ----
// in the max pass (a_src gather, cached to LDS); accumulate with 8-lane
// groups x ushort8 gathers, 16 records in flight per wave iteration.
__global__ __launch_bounds__(512) void k_aggB(const int* __restrict__ buf,
                                              const int* __restrict__ gcur,
                                              const float* __restrict__ a_src,
                                              const float* __restrict__ a_dst,
                                              const unsigned short* __restrict__ hb,
                                              const float* __restrict__ bias,
                                              float* __restrict__ out) {
    __shared__ int2 sorted[BCAP];    // .x = meta, .y = eval (filled in max pass)
    __shared__ int  scw[16 * 8];     // (bin, wave) counts -> inclusive scan
    __shared__ int  begs[17];
    int bk = blockIdx.x;
    int t = threadIdx.x;
    int w = t >> 6, lane = t & 63;
    int n = gcur[bk] - bk * BCAP;
    if (n > BCAP) n = BCAP;
    if (n < 0) n = 0;

    // phase 1: load my <=3 records (interleaved = coalesced), register hist
    const int* src = buf + (size_t)bk * BCAP;
    int r0 = 0, r1 = 0, r2 = 0;
    int bin0 = -1, bin1 = -1, bin2 = -1;
    if (t < n)        { r0 = src[t];        bin0 = (r0 >> 17) & 15; }
    if (t + 512 < n)  { r1 = src[t + 512];  bin1 = (r1 >> 17) & 15; }
    if (t + 1024 < n) { r2 = src[t + 1024]; bin2 = (r2 >> 17) & 15; }

    int h[16], incl[16];
#pragma unroll
    for (int i = 0; i < 16; ++i)
        h[i] = (bin0 == i) + (bin1 == i) + (bin2 == i);

    // phase 2a: per-bin inclusive shuffle-scan across the wave
#pragma unroll
    for (int i = 0; i < 16; ++i) {
        int v = h[i];
#pragma unroll
        for (int off = 1; off < 64; off <<= 1) {
            int u = __shfl_up(v, off, 64);
            if (lane >= off) v += u;
        }
        incl[i] = v;
        int tot = __shfl(v, 63, 64);
        if (lane == 0) scw[i * 8 + w] = tot;
    }
    __syncthreads();

    // phase 2b: inclusive block scan over scw[128] (bin-major, wave-minor)
    for (int off = 1; off < 128; off <<= 1) {
        int up = 0;
        if (t < 128 && t >= off) up = scw[t - off];
        __syncthreads();
        if (t < 128 && t >= off) scw[t] += up;
        __syncthreads();
    }
    if (t < 16) begs[t] = (t == 0) ? 0 : scw[t * 8 - 1];
    if (t == 16) begs[16] = n;

    // phase 3: place records (meta only)
    int p0 = 0, p1 = 0, p2 = 0;
#pragma unroll
    for (int i = 0; i < 16; ++i) {
        int idx = i * 8 + w;
        int base_i = ((idx ? scw[idx - 1] : 0)) + (incl[i] - h[i]);
        p0 += (bin0 == i) ? base_i : 0;
        p1 += (bin1 == i) ? base_i : 0;
        p2 += (bin2 == i) ? base_i : 0;
    }
    p1 += (bin1 == bin0);
    p2 += (bin2 == bin0) + (bin2 == bin1);
    if (bin0 >= 0) sorted[p0].x = r0;
    if (bin1 >= 0) sorted[p1].x = r1;
    if (bin2 >= 0) sorted[p2].x = r2;
    __syncthreads();

    // phase 4: wave w handles dsts 2w, 2w+1. 8-lane groups, ushort8 gathers.
    int g = lane >> 3, il = lane & 7;
    float4 bA = *(const float4*)(bias + 8 * il);
    float4 bB = *(const float4*)(bias + 8 * il + 4);
#pragma unroll
    for (int q = 0; q < 2; ++q) {
        int dlo = w * 2 + q;
        int beg = begs[dlo], end = begs[dlo + 1];
        float ad = a_dst[bk * 16 + dlo];

        // max pass: gather a_src, compute leaky-relu score, cache in .y
        float mx = -1e30f;
        for (int i = beg + lane; i < end; i += 64) {
            int meta = sorted[i].x;
            float v = a_src[meta & 0x1FFFF] + ad;
            v = v > 0.f ? v : NEG_SLOPE * v;
            sorted[i].y = __float_as_int(v);
            mx = fmaxf(mx, v);
        }
#pragma unroll
        for (int off = 32; off; off >>= 1) mx = fmaxf(mx, __shfl_xor(mx, off, 64));
        __builtin_amdgcn_wave_barrier();   // order eval writes before reads (intra-wave)

        float a0 = 0.f, a1 = 0.f, a2 = 0.f, a3 = 0.f;
        float a4c = 0.f, a5 = 0.f, a6 = 0.f, a7 = 0.f;
        float den = 0.f;
        int i = beg;
        for (; i + 16 <= end; i += 16) {
            int2 ra = sorted[i + g];
            int2 rb = sorted[i + 8 + g];
            const uint4 ha = *(const uint4*)(hb + (size_t)(ra.x & 0x1FFFF) * D + 8 * il);
            const uint4 hc = *(const uint4*)(hb + (size_t)(rb.x & 0x1FFFF) * D + 8 * il);
            float ea = __expf(__int_as_float(ra.y) - mx);
            float eb = __expf(__int_as_float(rb.y) - mx);
            a0 = fmaf(ea, blo(ha.x), a0); a1 = fmaf(ea, bhi(ha.x), a1);
            a2 = fmaf(ea, blo(ha.y), a2); a3 = fmaf(ea, bhi(ha.y), a3);
            a4c = fmaf(ea, blo(ha.z), a4c); a5 = fmaf(ea, bhi(ha.z), a5);
            a6 = fmaf(ea, blo(ha.w), a6); a7 = fmaf(ea, bhi(ha.w), a7);
            a0 = fmaf(eb, blo(hc.x), a0); a1 = fmaf(eb, bhi(hc.x), a1);
            a2 = fmaf(eb, blo(hc.y), a2); a3 = fmaf(eb, bhi(hc.y), a3);
            a4c = fmaf(eb, blo(hc.z), a4c); a5 = fmaf(eb, bhi(hc.z), a5);
            a6 = fmaf(eb, blo(hc.w), a6); a7 = fmaf(eb, bhi(hc.w), a7);
            den += ea + eb;
        }
        for (; i < end; i += 8) {            // guarded tail
            int idx = i + g;
            bool ok = idx < end;
            float e = 0.f;
            if (ok) {
                int2 r = sorted[idx];
                e = __expf(__int_as_float(r.y) - mx);
                const uint4 hv = *(const uint4*)(hb + (size_t)(r.x & 0x1FFFF) * D + 8 * il);
                a0 = fmaf(e, blo(hv.x), a0); a1 = fmaf(e, bhi(hv.x), a1);
                a2 = fmaf(e, blo(hv.y), a2); a3 = fmaf(e, bhi(hv.y), a3);
                a4c = fmaf(e, blo(hv.z), a4c); a5 = fmaf(e, bhi(hv.z), a5);
                a6 = fmaf(e, blo(hv.w), a6); a7 = fmaf(e, bhi(hv.w), a7);
            }
            den += e;
        }
        // combine the 8 record-groups: xor 8, 16, 32
#pragma unroll
        for (int off = 8; off <= 32; off <<= 1) {
            a0 += __shfl_xor(a0, off, 64); a1 += __shfl_xor(a1, off, 64);
            a2 += __shfl_xor(a2, off, 64); a3 += __shfl_xor(a3, off, 64);
            a4c += __shfl_xor(a4c, off, 64); a5 += __shfl_xor(a5, off, 64);
            a6 += __shfl_xor(a6, off, 64); a7 += __shfl_xor(a7, off, 64);
            den += __shfl_xor(den, off, 64);
        }
        if (g == 0) {
            float inv = 1.f / (den + 1e-16f);
            float4 oA, oB;
            oA.x = a0 * inv + bA.x; oA.y = a1 * inv + bA.y;
            oA.z = a2 * inv + bA.z; oA.w = a3 * inv + bA.w;
            oB.x = a4c * inv + bB.x; oB.y = a5 * inv + bB.y;
            oB.z = a6 * inv + bB.z; oB.w = a7 * inv + bB.w;
            float* orow = out + ((size_t)bk * 16 + dlo) * D + 8 * il;
            *(float4*)orow = oA;
            *(float4*)(orow + 4) = oB;
        }
    }
}

extern "C" void kernel_launch(void* const* d_in, const int* in_sizes, int n_in,
                              void* d_out, int out_size, void* d_ws, size_t ws_size,
                              hipStream_t stream) {
    const float* x        = (const float*)d_in[0];
    const int*   res_n_id = (const int*)d_in[1];
    const int*   edge_src = (const int*)d_in[2];
    const int*   edge_dst = (const int*)d_in[3];
    const float* W        = (const float*)d_in[4];
    const float* att_src  = (const float*)d_in[5];
    const float* att_dst  = (const float*)d_in[6];
    const float* bias     = (const float*)d_in[7];
    float* out = (float*)d_out;

    char* w = (char*)d_ws;
    unsigned short* hb = (unsigned short*)w; w += (size_t)N_SRC * D * 2;   // 12.8 MB
    int*   buf   = (int*)w;   w += (size_t)NBKT * BCAP * 4;                // 7.68 MB
    float* a_src = (float*)w; w += (size_t)N_SRC * 4;
    float* a_dst = (float*)w; w += (size_t)N_DST * 4;
    float* wad   = (float*)w; w += 256;
    int*   gcur  = (int*)w;   w += (size_t)NBKT * 4;

    k_wad_init<<<(NBKT + 255) / 256, 256, 0, stream>>>(W, att_dst, wad, gcur);
    k_h<<<(N_SRC + 63) / 64, 256, 0, stream>>>(x, W, att_src, hb, a_src);
    k_adst<<<N_DST / 4, 256, 0, stream>>>(x, res_n_id, wad, a_dst);
    k_bucket<<<(NE + TILE - 1) / TILE, 1024, 0, stream>>>(edge_src, edge_dst, gcur, buf);
    k_aggB<<<NBKT, 512, 0, stream>>>(buf, gcur, a_src, a_dst, hb, bias, out);
}

// Round 7
// 161.334 us; speedup vs baseline: 3.7651x; 1.0433x over previous
//
#include <hip/hip_runtime.h>

#define N_SRC 100000
#define N_DST 20000
#define NE    1250000
#define D     64
#define NEG_SLOPE 0.2f

#define NBKT 2500      // buckets of 8 dsts: bucket = dst >> 3
#define BCAP 768       // capacity per bucket (mean 500, ~12 sigma headroom)
#define TILE 4096      // edges per pass-A block

__device__ __forceinline__ unsigned short f2bf(float f) {
    unsigned u = __float_as_uint(f);
    u += 0x7FFFu + ((u >> 16) & 1);   // RNE
    return (unsigned short)(u >> 16);
}
__device__ __forceinline__ float blo(unsigned u) { return __uint_as_float(u << 16); }
__device__ __forceinline__ float bhi(unsigned u) { return __uint_as_float(u & 0xFFFF0000u); }

// ---- K0: wad[k] = W[k,:]@att_dst  +  init bucket cursors ----
__global__ void k_wad_init(const float* __restrict__ W,
                           const float* __restrict__ att_dst,
                           float* __restrict__ wad, int* __restrict__ gcur) {
    int g = blockIdx.x * 256 + threadIdx.x;
    if (g < NBKT) gcur[g] = g * BCAP;
    if (g < D) {
        float s = 0.f;
#pragma unroll
        for (int c = 0; c < D; ++c) s += W[g * D + c] * att_dst[c];
        wad[g] = s;
    }
}

// ---- K1: h = x @ W (bf16 out), a_src = h @ att_src. ----
// 64x64 tile, 4x4 reg; x-tile stored k-major so inner loop is 2x ds_read_b128.
__global__ __launch_bounds__(256) void k_h(const float* __restrict__ x,
                                           const float* __restrict__ W,
                                           const float* __restrict__ att_src,
                                           unsigned short* __restrict__ hb,
                                           float* __restrict__ a_src) {
    __shared__ float xs[64 * 68];   // xs[k*68 + r] = x[row0+r][k]
    __shared__ float Ws[64 * 64];
    int t = threadIdx.x;
    int row0 = blockIdx.x * 64;
    int nrows = N_SRC - row0; if (nrows > 64) nrows = 64;
    {
        const float4* W4 = (const float4*)W;
        float4* Ws4 = (float4*)Ws;
#pragma unroll
        for (int p = 0; p < 4; ++p) Ws4[t + 256 * p] = W4[t + 256 * p];
    }
#pragma unroll
    for (int p = 0; p < 4; ++p) {
        int idx = t + 256 * p;            // 0..1023
        int r = idx >> 4, kq = idx & 15;
        float4 v = make_float4(0.f, 0.f, 0.f, 0.f);
        if (r < nrows) v = *(const float4*)(x + (size_t)(row0 + r) * D + 4 * kq);
        xs[(4 * kq + 0) * 68 + r] = v.x;
        xs[(4 * kq + 1) * 68 + r] = v.y;
        xs[(4 * kq + 2) * 68 + r] = v.z;
        xs[(4 * kq + 3) * 68 + r] = v.w;
    }
    __syncthreads();
    int ry = t >> 4, cx = t & 15;         // thread: rows 4ry..+3, cols 4cx..+3
    float acc[4][4] = {{0.f}};
#pragma unroll 8
    for (int k = 0; k < 64; ++k) {
        float4 xv = *(const float4*)(xs + k * 68 + 4 * ry);
        float4 wv = *(const float4*)(Ws + k * 64 + 4 * cx);
        acc[0][0] = fmaf(xv.x, wv.x, acc[0][0]); acc[0][1] = fmaf(xv.x, wv.y, acc[0][1]);
        acc[0][2] = fmaf(xv.x, wv.z, acc[0][2]); acc[0][3] = fmaf(xv.x, wv.w, acc[0][3]);
        acc[1][0] = fmaf(xv.y, wv.x, acc[1][0]); acc[1][1] = fmaf(xv.y, wv.y, acc[1][1]);
        acc[1][2] = fmaf(xv.y, wv.z, acc[1][2]); acc[1][3] = fmaf(xv.y, wv.w, acc[1][3]);
        acc[2][0] = fmaf(xv.z, wv.x, acc[2][0]); acc[2][1] = fmaf(xv.z, wv.y, acc[2][1]);
        acc[2][2] = fmaf(xv.z, wv.z, acc[2][2]); acc[2][3] = fmaf(xv.z, wv.w, acc[2][3]);
        acc[3][0] = fmaf(xv.w, wv.x, acc[3][0]); acc[3][1] = fmaf(xv.w, wv.y, acc[3][1]);
        acc[3][2] = fmaf(xv.w, wv.z, acc[3][2]); acc[3][3] = fmaf(xv.w, wv.w, acc[3][3]);
    }
    float4 a4 = *(const float4*)(att_src + 4 * cx);
#pragma unroll
    for (int j = 0; j < 4; ++j) {
        int r = 4 * ry + j;
        if (r < nrows) {
            ushort4 hv;
            hv.x = f2bf(acc[j][0]); hv.y = f2bf(acc[j][1]);
            hv.z = f2bf(acc[j][2]); hv.w = f2bf(acc[j][3]);
            *(ushort4*)(hb + (size_t)(row0 + r) * D + 4 * cx) = hv;
        }
        float p = acc[j][0] * a4.x + acc[j][1] * a4.y + acc[j][2] * a4.z + acc[j][3] * a4.w;
        p += __shfl_xor(p, 1, 64); p += __shfl_xor(p, 2, 64);
        p += __shfl_xor(p, 4, 64); p += __shfl_xor(p, 8, 64);
        if (cx == 0 && r < nrows) a_src[row0 + r] = p;
    }
}

// ---- K3 (pass A): LDS-staged multi-split of edges into NBKT buckets ----
// record int: src(17b) | dst_lo3(3b)<<17 | bucket(12b)<<20
__global__ __launch_bounds__(1024) void k_bucket(const int* __restrict__ es,
                                                 const int* __restrict__ ed,
                                                 int* __restrict__ gcur,
                                                 int* __restrict__ buf) {
    __shared__ int hist[NBKT];
    __shared__ int lofs[NBKT];
    __shared__ int gbase[NBKT];
    __shared__ int wtot[16];
    __shared__ int stage[TILE];
    int t = threadIdx.x;
    int w = t >> 6, lane = t & 63;
    int base = blockIdx.x * TILE;
    int nE = NE - base; if (nE > TILE) nE = TILE;

    for (int i = t; i < NBKT; i += 1024) hist[i] = 0;
    __syncthreads();

    int s_[4], d_[4], rk_[4];
#pragma unroll
    for (int j = 0; j < 4; ++j) {
        int i = t + 1024 * j;
        d_[j] = -1;
        if (i < nE) {
            s_[j] = es[base + i];
            d_[j] = ed[base + i];
            rk_[j] = atomicAdd(&hist[d_[j] >> 3], 1);   // rank within bucket
        }
    }
    __syncthreads();

    // exclusive scan of hist: 3 buckets/thread (834 threads active)
    int c0 = t * 3;
    int hc[3] = {0, 0, 0};
#pragma unroll
    for (int j = 0; j < 3; ++j)
        if (c0 + j < NBKT) hc[j] = hist[c0 + j];
    int sum = hc[0] + hc[1] + hc[2];
    int incl = sum;
#pragma unroll
    for (int off = 1; off < 64; off <<= 1) {
        int u = __shfl_up(incl, off, 64);
        if (lane >= off) incl += u;
    }
    if (lane == 63) wtot[w] = incl;
    __syncthreads();
    int wpre = 0;
#pragma unroll
    for (int j = 0; j < 16; ++j) wpre += (j < w) ? wtot[j] : 0;
    {
        int run = wpre + incl - sum;
#pragma unroll
        for (int j = 0; j < 3; ++j) {
            int b = c0 + j;
            if (b < NBKT) {
                lofs[b] = run;
                gbase[b] = hc[j] ? atomicAdd(&gcur[b], hc[j]) : 0;
                run += hc[j];
            }
        }
    }
    __syncthreads();

#pragma unroll
    for (int j = 0; j < 4; ++j) {
        if (d_[j] >= 0) {
            int b = d_[j] >> 3;
            stage[lofs[b] + rk_[j]] = s_[j] | ((d_[j] & 7) << 17) | (b << 20);
        }
    }
    __syncthreads();

    for (int idx = t; idx < nE; idx += 1024) {
        int rec = stage[idx];
        int b = ((unsigned)rec) >> 20;
        int gpos = gbase[b] + idx - lofs[b];
        if (gpos < (b + 1) * BCAP) buf[gpos] = rec;   // coalesced runs
    }
}

// ---- K4 (pass B): counting-sort bucket (8 bins) in LDS; a_dst computed ----
// inline; scores in max pass; 8-lane groups x ushort8 gathers, 32 deep.
__global__ __launch_bounds__(256) void k_aggB(const int* __restrict__ buf,
                                              const int* __restrict__ gcur,
                                              const float* __restrict__ a_src,
                                              const float* __restrict__ x,
                                              const int* __restrict__ res_n_id,
                                              const float* __restrict__ wad,
                                              const unsigned short* __restrict__ hb,
                                              const float* __restrict__ bias,
                                              float* __restrict__ out) {
    __shared__ int2 sorted[BCAP];    // .x = meta, .y = eval (filled in max pass)
    __shared__ int  scw[8 * 4];      // (bin, wave) counts -> inclusive scan
    __shared__ int  begs[9];
    int bk = blockIdx.x;
    int t = threadIdx.x;
    int w = t >> 6, lane = t & 63;
    int n = gcur[bk] - bk * BCAP;
    if (n > BCAP) n = BCAP;
    if (n < 0) n = 0;

    // phase 1: load my <=3 records (interleaved = coalesced), register hist
    const int* src = buf + (size_t)bk * BCAP;
    int r0 = 0, r1 = 0, r2 = 0;
    int bin0 = -1, bin1 = -1, bin2 = -1;
    if (t < n)       { r0 = src[t];       bin0 = (r0 >> 17) & 7; }
    if (t + 256 < n) { r1 = src[t + 256]; bin1 = (r1 >> 17) & 7; }
    if (t + 512 < n) { r2 = src[t + 512]; bin2 = (r2 >> 17) & 7; }

    int h[8], incl[8];
#pragma unroll
    for (int i = 0; i < 8; ++i)
        h[i] = (bin0 == i) + (bin1 == i) + (bin2 == i);

    // phase 2a: per-bin inclusive shuffle-scan across the wave
#pragma unroll
    for (int i = 0; i < 8; ++i) {
        int v = h[i];
#pragma unroll
        for (int off = 1; off < 64; off <<= 1) {
            int u = __shfl_up(v, off, 64);
            if (lane >= off) v += u;
        }
        incl[i] = v;
        int tot = __shfl(v, 63, 64);
        if (lane == 0) scw[i * 4 + w] = tot;
    }
    __syncthreads();

    // phase 2b: inclusive scan over scw[32] in wave 0
    if (t < 32) {
        int v = scw[t];
#pragma unroll
        for (int off = 1; off < 32; off <<= 1) {
            int u = __shfl_up(v, off, 64);
            if (t >= off) v += u;
        }
        scw[t] = v;
    }
    __syncthreads();
    if (t < 8) begs[t] = (t == 0) ? 0 : scw[t * 4 - 1];
    if (t == 8) begs[8] = n;

    // phase 3: place records (meta only)
    int p0 = 0, p1 = 0, p2 = 0;
#pragma unroll
    for (int i = 0; i < 8; ++i) {
        int idx = i * 4 + w;
        int base_i = ((idx ? scw[idx - 1] : 0)) + (incl[i] - h[i]);
        p0 += (bin0 == i) ? base_i : 0;
        p1 += (bin1 == i) ? base_i : 0;
        p2 += (bin2 == i) ? base_i : 0;
    }
    p1 += (bin1 == bin0);
    p2 += (bin2 == bin0) + (bin2 == bin1);
    if (bin0 >= 0) sorted[p0].x = r0;
    if (bin1 >= 0) sorted[p1].x = r1;
    if (bin2 >= 0) sorted[p2].x = r2;
    float wv = wad[lane];            // overlap with sort barriers
    __syncthreads();

    // phase 4: wave w handles dsts 2w, 2w+1. 8-lane groups, ushort8 gathers.
    int g = lane >> 3, il = lane & 7;
    float4 bA = *(const float4*)(bias + 8 * il);
    float4 bB = *(const float4*)(bias + 8 * il + 4);
#pragma unroll
    for (int q = 0; q < 2; ++q) {
        int dlo = w * 2 + q;
        int beg = begs[dlo], end = begs[dlo + 1];

        // a_dst inline: one coalesced x-row load + butterfly dot with wad
        int xrow = res_n_id[bk * 8 + dlo];
        float ad = x[(size_t)xrow * D + lane] * wv;
#pragma unroll
        for (int off = 32; off; off >>= 1) ad += __shfl_xor(ad, off, 64);

        // max pass: gather a_src, leaky-relu score, cache in .y
        float mx = -1e30f;
        for (int i = beg + lane; i < end; i += 64) {
            int meta = sorted[i].x;
            float v = a_src[meta & 0x1FFFF] + ad;
            v = v > 0.f ? v : NEG_SLOPE * v;
            sorted[i].y = __float_as_int(v);
            mx = fmaxf(mx, v);
        }
#pragma unroll
        for (int off = 32; off; off >>= 1) mx = fmaxf(mx, __shfl_xor(mx, off, 64));
        __builtin_amdgcn_wave_barrier();   // order eval writes before reads (intra-wave)

        float a0 = 0.f, a1 = 0.f, a2 = 0.f, a3 = 0.f;
        float a4c = 0.f, a5 = 0.f, a6 = 0.f, a7 = 0.f;
        float den = 0.f;
        int i = beg;
        for (; i + 32 <= end; i += 32) {   // 4 loads in flight per lane
            int2 ra = sorted[i + g];
            int2 rb = sorted[i + 8 + g];
            int2 rc = sorted[i + 16 + g];
            int2 rd = sorted[i + 24 + g];
            const uint4 ha = *(const uint4*)(hb + (size_t)(ra.x & 0x1FFFF) * D + 8 * il);
            const uint4 hc4 = *(const uint4*)(hb + (size_t)(rb.x & 0x1FFFF) * D + 8 * il);
            const uint4 he = *(const uint4*)(hb + (size_t)(rc.x & 0x1FFFF) * D + 8 * il);
            const uint4 hf = *(const uint4*)(hb + (size_t)(rd.x & 0x1FFFF) * D + 8 * il);
            float ea = __expf(__int_as_float(ra.y) - mx);
            float eb = __expf(__int_as_float(rb.y) - mx);
            float ec = __expf(__int_as_float(rc.y) - mx);
            float ed = __expf(__int_as_float(rd.y) - mx);
            a0 = fmaf(ea, blo(ha.x), a0); a1 = fmaf(ea, bhi(ha.x), a1);
            a2 = fmaf(ea, blo(ha.y), a2); a3 = fmaf(ea, bhi(ha.y), a3);
            a4c = fmaf(ea, blo(ha.z), a4c); a5 = fmaf(ea, bhi(ha.z), a5);
            a6 = fmaf(ea, blo(ha.w), a6); a7 = fmaf(ea, bhi(ha.w), a7);
            a0 = fmaf(eb, blo(hc4.x), a0); a1 = fmaf(eb, bhi(hc4.x), a1);
            a2 = fmaf(eb, blo(hc4.y), a2); a3 = fmaf(eb, bhi(hc4.y), a3);
            a4c = fmaf(eb, blo(hc4.z), a4c); a5 = fmaf(eb, bhi(hc4.z), a5);
            a6 = fmaf(eb, blo(hc4.w), a6); a7 = fmaf(eb, bhi(hc4.w), a7);
            a0 = fmaf(ec, blo(he.x), a0); a1 = fmaf(ec, bhi(he.x), a1);
            a2 = fmaf(ec, blo(he.y), a2); a3 = fmaf(ec, bhi(he.y), a3);
            a4c = fmaf(ec, blo(he.z), a4c); a5 = fmaf(ec, bhi(he.z), a5);
            a6 = fmaf(ec, blo(he.w), a6); a7 = fmaf(ec, bhi(he.w), a7);
            a0 = fmaf(ed, blo(hf.x), a0); a1 = fmaf(ed, bhi(hf.x), a1);
            a2 = fmaf(ed, blo(hf.y), a2); a3 = fmaf(ed, bhi(hf.y), a3);
            a4c = fmaf(ed, blo(hf.z), a4c); a5 = fmaf(ed, bhi(hf.z), a5);
            a6 = fmaf(ed, blo(hf.w), a6); a7 = fmaf(ed, bhi(hf.w), a7);
            den += (ea + eb) + (ec + ed);
        }
        for (; i + 16 <= end; i += 16) {   // 2 loads in flight
            int2 ra = sorted[i + g];
            int2 rb = sorted[i + 8 + g];
            const uint4 ha = *(const uint4*)(hb + (size_t)(ra.x & 0x1FFFF) * D + 8 * il);
            const uint4 hc4 = *(const uint4*)(hb + (size_t)(rb.x & 0x1FFFF) * D + 8 * il);
            float ea = __expf(__int_as_float(ra.y) - mx);
            float eb = __expf(__int_as_float(rb.y) - mx);
            a0 = fmaf(ea, blo(ha.x), a0); a1 = fmaf(ea, bhi(ha.x), a1);
            a2 = fmaf(ea, blo(ha.y), a2); a3 = fmaf(ea, bhi(ha.y), a3);
            a4c = fmaf(ea, blo(ha.z), a4c); a5 = fmaf(ea, bhi(ha.z), a5);
            a6 = fmaf(ea, blo(ha.w), a6); a7 = fmaf(ea, bhi(ha.w), a7);
            a0 = fmaf(eb, blo(hc4.x), a0); a1 = fmaf(eb, bhi(hc4.x), a1);
            a2 = fmaf(eb, blo(hc4.y), a2); a3 = fmaf(eb, bhi(hc4.y), a3);
            a4c = fmaf(eb, blo(hc4.z), a4c); a5 = fmaf(eb, bhi(hc4.z), a5);
            a6 = fmaf(eb, blo(hc4.w), a6); a7 = fmaf(eb, bhi(hc4.w), a7);
            den += ea + eb;
        }
        for (; i < end; i += 8) {          // guarded tail
            int idx = i + g;
            bool ok = idx < end;
            float e = 0.f;
            if (ok) {
                int2 r = sorted[idx];
                e = __expf(__int_as_float(r.y) - mx);
                const uint4 hv = *(const uint4*)(hb + (size_t)(r.x & 0x1FFFF) * D + 8 * il);
                a0 = fmaf(e, blo(hv.x), a0); a1 = fmaf(e, bhi(hv.x), a1);
                a2 = fmaf(e, blo(hv.y), a2); a3 = fmaf(e, bhi(hv.y), a3);
                a4c = fmaf(e, blo(hv.z), a4c); a5 = fmaf(e, bhi(hv.z), a5);
                a6 = fmaf(e, blo(hv.w), a6); a7 = fmaf(e, bhi(hv.w), a7);
            }
            den += e;
        }
        // combine the 8 record-groups: xor 8, 16, 32
#pragma unroll
        for (int off = 8; off <= 32; off <<= 1) {
            a0 += __shfl_xor(a0, off, 64); a1 += __shfl_xor(a1, off, 64);
            a2 += __shfl_xor(a2, off, 64); a3 += __shfl_xor(a3, off, 64);
            a4c += __shfl_xor(a4c, off, 64); a5 += __shfl_xor(a5, off, 64);
            a6 += __shfl_xor(a6, off, 64); a7 += __shfl_xor(a7, off, 64);
            den += __shfl_xor(den, off, 64);
        }
        if (g == 0) {
            float inv = 1.f / (den + 1e-16f);
            float4 oA, oB;
            oA.x = a0 * inv + bA.x; oA.y = a1 * inv + bA.y;
            oA.z = a2 * inv + bA.z; oA.w = a3 * inv + bA.w;
            oB.x = a4c * inv + bB.x; oB.y = a5 * inv + bB.y;
            oB.z = a6 * inv + bB.z; oB.w = a7 * inv + bB.w;
            float* orow = out + ((size_t)bk * 8 + dlo) * D + 8 * il;
            *(float4*)orow = oA;
            *(float4*)(orow + 4) = oB;
        }
    }
}

extern "C" void kernel_launch(void* const* d_in, const int* in_sizes, int n_in,
                              void* d_out, int out_size, void* d_ws, size_t ws_size,
                              hipStream_t stream) {
    const float* x        = (const float*)d_in[0];
    const int*   res_n_id = (const int*)d_in[1];
    const int*   edge_src = (const int*)d_in[2];
    const int*   edge_dst = (const int*)d_in[3];
    const float* W        = (const float*)d_in[4];
    const float* att_src  = (const float*)d_in[5];
    const float* att_dst  = (const float*)d_in[6];
    const float* bias     = (const float*)d_in[7];
    float* out = (float*)d_out;

    char* w = (char*)d_ws;
    unsigned short* hb = (unsigned short*)w; w += (size_t)N_SRC * D * 2;   // 12.8 MB
    int*   buf   = (int*)w;   w += (size_t)NBKT * BCAP * 4;                // 7.68 MB
    float* a_src = (float*)w; w += (size_t)N_SRC * 4;
    float* wad   = (float*)w; w += 256;
    int*   gcur  = (int*)w;   w += (size_t)NBKT * 4;

    k_wad_init<<<(NBKT + 255) / 256, 256, 0, stream>>>(W, att_dst, wad, gcur);
    k_h<<<(N_SRC + 63) / 64, 256, 0, stream>>>(x, W, att_src, hb, a_src);
    k_bucket<<<(NE + TILE - 1) / TILE, 1024, 0, stream>>>(edge_src, edge_dst, gcur, buf);
    k_aggB<<<NBKT, 256, 0, stream>>>(buf, gcur, a_src, x, res_n_id, wad, hb, bias, out);
}